// Round 18
// baseline (265.859 us; speedup 1.0000x reference)
//
#include <hip/hip_runtime.h>

typedef __attribute__((ext_vector_type(4))) float f32x4;

#define NT 256
#define S 10
#define D 100
#define H 16
#define NITER 5
#define QPR 25   // quads per corpus s-row (100 floats); also out-staging stride
#define RQ 25
#define OUTQ 24  // quads per output row (6*16 floats)

// Wave-uniform weight/bias reads straight from global (scalar/constant
// cache path; no LDS weight tile -> no promotion balloon -> no spill).
#define WQ(base, d, q) (*(const f32x4*)&(base)[(d) * H + (q) * 4])

__global__ __launch_bounds__(NT, 1)
void attn_greedy_kernel(const float* __restrict__ user_intent,
                        const float* __restrict__ item_corpus,
                        const float* __restrict__ W_proj,
                        const float* __restrict__ b_proj,
                        const float* __restrict__ W_k,
                        const float* __restrict__ b_k,
                        float* __restrict__ out)
{
    // 102,400 B: corpus s-chunk during projection, output staging after.
    __shared__ f32x4 smem[NT * QPR];

    const int t = threadIdx.x;
    const size_t b0 = (size_t)blockIdx.x * NT;   // 256 rows per block
    const size_t b = b0 + t;                     // this thread's row

    // biases: uniform -> scalar regs
    f32x4 bp[4], bk[4];
    #pragma unroll
    for (int q = 0; q < 4; ++q) {
        bp[q] = *(const f32x4*)&b_proj[q * 4];
        bk[q] = *(const f32x4*)&b_k[q * 4];
    }

    // user_intent: one full 64B line per lane (coalesced)
    const f32x4* urow = (const f32x4*)user_intent + b * 4;
    f32x4 usum[4];
    #pragma unroll
    for (int q = 0; q < 4; ++q) usum[q] = urow[q];

    // ---- Projection via COALESCED chunked staging. Chunk s = the block's
    // 256 rows' s-slice (6400 quads). Raster map: qidx = j*256+t -> (r,i)
    // with r=qidx/25, i=qidx%25; global quad = (b0+r)*250 + s*25 + i ->
    // consecutive lanes hit consecutive addresses in 400B runs (a wave
    // touches ~20 fully-consumed lines, vs 64 scattered lines in r1-r17:
    // the plateau's cause). LDS slot = qidx == r*25+i (row-major, s-slice).
    const f32x4* gbase = (const f32x4*)item_corpus + b0 * (S * QPR);
    const int r0 = t / QPR, i0 = t - r0 * QPR;

    f32x4 ic[S][4];
    #pragma unroll 1
    for (int s = 0; s < S; ++s) {
        {   // stage chunk s (25 coalesced wave-loads, all independent)
            int r = r0, i = i0;
            #pragma unroll
            for (int j = 0; j < QPR; ++j) {
                smem[j * NT + t] = gbase[(size_t)r * (S * QPR) + s * QPR + i];
                // qidx advances by 256 = 10*25 + 6 (branch-free carry)
                i += 6; r += 10;
                int ov = (i >= QPR) ? 1 : 0;
                i -= ov * QPR; r += ov;
            }
        }
        __syncthreads();
        {   // consume: project this thread's row (d-ascending, bit-identical)
            f32x4 a0 = bp[0], a1 = bp[1], a2 = bp[2], a3 = bp[3];
            #pragma unroll
            for (int i = 0; i < QPR; ++i) {
                f32x4 c = smem[t * QPR + i];
                #pragma unroll
                for (int dd = 0; dd < 4; ++dd) {
                    float a = c[dd];
                    const int d = i * 4 + dd;
                    a0 += a * WQ(W_proj, d, 0);
                    a1 += a * WQ(W_proj, d, 1);
                    a2 += a * WQ(W_proj, d, 2);
                    a3 += a * WQ(W_proj, d, 3);
                }
            }
            ic[s][0] = a0; ic[s][1] = a1; ic[s][2] = a2; ic[s][3] = a3;
        }
        __syncthreads();   // buffer reused by next chunk / by out staging
    }

    // smem now free: it becomes out staging (row stride RQ==QPR quads).
    #pragma unroll
    for (int q = 0; q < 4; ++q) smem[t * RQ + q] = usum[q];   // ui[:,0,:]

    // ---- Greedy iterations: r10's verified in-lane phase, verbatim.
    #pragma unroll 1
    for (int it = 0; it < NITER; ++it) {
        // ic = ic @ Wk + bk, per-s IN PLACE (k ascending -> bit-identical)
        #pragma unroll
        for (int s = 0; s < S; ++s) {
            f32x4 n0 = bk[0], n1 = bk[1], n2 = bk[2], n3 = bk[3];
            #pragma unroll
            for (int k = 0; k < H; ++k) {
                float a = ic[s][k >> 2][k & 3];
                n0 += a * WQ(W_k, k, 0);
                n1 += a * WQ(W_k, k, 1);
                n2 += a * WQ(W_k, k, 2);
                n3 += a * WQ(W_k, k, 3);
            }
            ic[s][0] = n0; ic[s][1] = n1; ic[s][2] = n2; ic[s][3] = n3;
        }

        // src = mean(ui)
        float cnt = (float)(it + 1);
        f32x4 src[4];
        #pragma unroll
        for (int q = 0; q < 4; ++q) src[q] = usum[q] / cnt;

        // scores + first-max argmax (softmax skipped: monotonic)
        float best = 0.0f;
        int bidx = 0;
        #pragma unroll
        for (int s = 0; s < S; ++s) {
            float sc = 0.0f;
            #pragma unroll
            for (int q = 0; q < 4; ++q)
                #pragma unroll
                for (int c = 0; c < 4; ++c)
                    sc += ic[s][q][c] * src[q][c];
            if (s == 0 || sc > best) { best = sc; bidx = s; }
        }

        // item_vec = ic[bidx] via unrolled select (static register indexing)
        f32x4 iv[4];
        #pragma unroll
        for (int q = 0; q < 4; ++q) iv[q] = ic[0][q];
        #pragma unroll
        for (int s = 1; s < S; ++s) {
            bool take = (bidx == s);
            #pragma unroll
            for (int q = 0; q < 4; ++q)
                iv[q] = take ? ic[s][q] : iv[q];
        }

        #pragma unroll
        for (int q = 0; q < 4; ++q) {
            usum[q] += iv[q];
            smem[t * RQ + (it + 1) * 4 + q] = iv[q];
        }
    }

    // ---- Coalesced output: 256 rows x 24 quads contiguous per block.
    __syncthreads();
    f32x4* out4 = (f32x4*)out;
    const size_t obase = b0 * OUTQ;
    #pragma unroll
    for (int k = 0; k < OUTQ; ++k) {
        int j = t + k * NT;
        int row = j / OUTQ;
        int q = j - row * OUTQ;
        out4[obase + j] = smem[row * RQ + q];
    }
}

extern "C" void kernel_launch(void* const* d_in, const int* in_sizes, int n_in,
                              void* d_out, int out_size, void* d_ws, size_t ws_size,
                              hipStream_t stream) {
    const float* user_intent = (const float*)d_in[0];
    const float* item_corpus = (const float*)d_in[1];
    const float* W_proj      = (const float*)d_in[2];
    const float* b_proj      = (const float*)d_in[3];
    const float* W_k         = (const float*)d_in[4];
    const float* b_k         = (const float*)d_in[5];
    float* out = (float*)d_out;

    const int bs = 65536;
    hipLaunchKernelGGL(attn_greedy_kernel,
                       dim3(bs / NT), dim3(NT), 0, stream,
                       user_intent, item_corpus, W_proj, b_proj, W_k, b_k, out);
}

// Round 19
// 126.364 us; speedup vs baseline: 2.1039x; 2.1039x over previous
//
#include <hip/hip_runtime.h>

typedef __attribute__((ext_vector_type(4))) float f32x4;

#define NT 256
#define S 10
#define D 100
#define H 16
#define NITER 5
#define LPR 4               // lanes cooperating on one batch row
#define RPB (NT / LPR)      // 64 batch rows per block
#define RQ 25               // out-staging row stride in quads (24 + 1 pad)
#define OUTQ 24             // quads per output row (6*16 floats)

__global__ __launch_bounds__(NT, 1)
void attn_greedy_kernel(const float* __restrict__ user_intent,
                        const float* __restrict__ item_corpus,
                        const float* __restrict__ W_proj,
                        const float* __restrict__ b_proj,
                        const float* __restrict__ W_k,
                        const float* __restrict__ b_k,
                        float* __restrict__ out)
{
    // Weights in LDS: uniform-address broadcast ds_reads (no TA lane-requests
    // -- the r11-r17 plateau's cause was per-lane VMEM weight loads).
    // Laundered offsets (r9's proven trick) prevent the register-promotion
    // balloon that caused the r1-r7 spill saga.
    __shared__ f32x4 s_wp[D * 4];          // wp[d][q]  6400 B
    __shared__ f32x4 s_wk[H * 4];          // wk[k][q]  1024 B
    __shared__ f32x4 s_out[RPB * RQ];      // 25.6 KB out staging

    {
        float* wpf = (float*)s_wp;
        for (int i = threadIdx.x; i < D * H; i += NT) wpf[i] = W_proj[i];
        float* wkf = (float*)s_wk;
        for (int i = threadIdx.x; i < H * H; i += NT) wkf[i] = W_k[i];
    }
    __syncthreads();

    const int t = threadIdx.x;
    const int quarter = t & 3;             // lane within the 4-lane row group
    const int r = t >> 2;                  // batch row within block
    const size_t b = (size_t)blockIdx.x * RPB + r;
    // rows per lane: {3,3,2,2}; global s start: {0,3,6,8}
    const bool has3 = (quarter < 2);
    const int sbase = has3 ? quarter * 3 : 2 + quarter * 2;

    const f32x4* crow = (const f32x4*)item_corpus + b * (S * D / 4) + sbase * (D / 4);
    // third-row base clamped in-bounds for !has3 lanes (r13 trick): its ic[2]
    // is computed but never consumed (all downstream uses guarded).
    const int r2 = has3 ? 2 * (D / 4) : (D / 4);

    // biases: uniform -> scalar path (tiny, one-time)
    f32x4 bp[4];
    #pragma unroll
    for (int q = 0; q < 4; ++q) bp[q] = *(const f32x4*)&b_proj[q * 4];

    // user_intent: all 4 lanes hold the row (same cache line; broadcast).
    const f32x4* urow = (const f32x4*)user_intent + b * 4;
    f32x4 usum[4];
    #pragma unroll
    for (int q = 0; q < 4; ++q) {
        usum[q] = urow[q];
        if (quarter == 0) s_out[r * RQ + q] = usum[q];   // ui[:,0,:]
    }

    // ---- Projection: chunks of 4 corpus quads (one FULL 64B line per row,
    // consumed in one visit -> no r13 refetch). Weight quads read ONCE per d
    // from LDS (laundered) and shared across all 3 rows. d-ascending
    // accumulation -> bit-identical to all passing rounds.
    f32x4 ic[3][4];
    #pragma unroll
    for (int ls = 0; ls < 3; ++ls)
        #pragma unroll
        for (int q = 0; q < 4; ++q) ic[ls][q] = bp[q];

    #pragma unroll 1
    for (int ch = 0; ch < 6; ++ch) {       // 6 chunks x 4 quads (d 0..95)
        f32x4 c0[4], c1[4], c2[4];
        #pragma unroll
        for (int j = 0; j < 4; ++j) {      // 12 independent line-burst loads
            c0[j] = crow[ch * 4 + j];
            c1[j] = crow[(D / 4) + ch * 4 + j];
            c2[j] = crow[r2 + ch * 4 + j];
        }
        #pragma unroll
        for (int j = 0; j < 4; ++j)
            #pragma unroll
            for (int dd = 0; dd < 4; ++dd) {
                int off = ((ch * 4 + j) * 4 + dd) * 4;
                asm volatile("" : "+v"(off));          // kill cross-d CSE
                f32x4 w0 = s_wp[off + 0], w1 = s_wp[off + 1];
                f32x4 w2 = s_wp[off + 2], w3 = s_wp[off + 3];
                float a0 = c0[j][dd], a1 = c1[j][dd], a2 = c2[j][dd];
                ic[0][0] += a0 * w0; ic[0][1] += a0 * w1;
                ic[0][2] += a0 * w2; ic[0][3] += a0 * w3;
                ic[1][0] += a1 * w0; ic[1][1] += a1 * w1;
                ic[1][2] += a1 * w2; ic[1][3] += a1 * w3;
                ic[2][0] += a2 * w0; ic[2][1] += a2 * w1;
                ic[2][2] += a2 * w2; ic[2][3] += a2 * w3;
            }
    }
    {   // tail: quad 24 (d 96..99)
        f32x4 c0 = crow[24], c1 = crow[(D / 4) + 24], c2 = crow[r2 + 24];
        #pragma unroll
        for (int dd = 0; dd < 4; ++dd) {
            int off = (96 + dd) * 4;
            asm volatile("" : "+v"(off));
            f32x4 w0 = s_wp[off + 0], w1 = s_wp[off + 1];
            f32x4 w2 = s_wp[off + 2], w3 = s_wp[off + 3];
            float a0 = c0[dd], a1 = c1[dd], a2 = c2[dd];
            ic[0][0] += a0 * w0; ic[0][1] += a0 * w1;
            ic[0][2] += a0 * w2; ic[0][3] += a0 * w3;
            ic[1][0] += a1 * w0; ic[1][1] += a1 * w1;
            ic[1][2] += a1 * w2; ic[1][3] += a1 * w3;
            ic[2][0] += a2 * w0; ic[2][1] += a2 * w1;
            ic[2][2] += a2 * w2; ic[2][3] += a2 * w3;
        }
    }

    f32x4 bk[4];
    #pragma unroll
    for (int q = 0; q < 4; ++q) bk[q] = *(const f32x4*)&b_k[q * 4];

    // ---- Greedy iterations. Matvec: kc fully unrolled (static ic indices,
    // rule #20), laundered 8-quad wk chunks shared across all 3 rows via
    // n[3][4]. k-ascending accumulation -> bit-identical.
    #pragma unroll 1
    for (int it = 0; it < NITER; ++it) {
        f32x4 n[3][4];
        #pragma unroll
        for (int ls = 0; ls < 3; ++ls)
            #pragma unroll
            for (int q = 0; q < 4; ++q) n[ls][q] = bk[q];

        #pragma unroll
        for (int kc = 0; kc < 8; ++kc) {   // k = 2*kc, 2*kc+1
            int off = kc * 8;
            asm volatile("" : "+v"(off));  // kill cross-chunk CSE
            f32x4 wa0 = s_wk[off + 0], wa1 = s_wk[off + 1];
            f32x4 wa2 = s_wk[off + 2], wa3 = s_wk[off + 3];
            f32x4 wb0 = s_wk[off + 4], wb1 = s_wk[off + 5];
            f32x4 wb2 = s_wk[off + 6], wb3 = s_wk[off + 7];
            {   // k = 2*kc (static index: kc is a compile-time constant)
                float x0 = ic[0][(2 * kc) >> 2][(2 * kc) & 3];
                float x1 = ic[1][(2 * kc) >> 2][(2 * kc) & 3];
                float x2 = ic[2][(2 * kc) >> 2][(2 * kc) & 3];
                n[0][0] += x0 * wa0; n[0][1] += x0 * wa1;
                n[0][2] += x0 * wa2; n[0][3] += x0 * wa3;
                n[1][0] += x1 * wa0; n[1][1] += x1 * wa1;
                n[1][2] += x1 * wa2; n[1][3] += x1 * wa3;
                n[2][0] += x2 * wa0; n[2][1] += x2 * wa1;
                n[2][2] += x2 * wa2; n[2][3] += x2 * wa3;
            }
            {   // k = 2*kc+1
                float x0 = ic[0][(2 * kc + 1) >> 2][(2 * kc + 1) & 3];
                float x1 = ic[1][(2 * kc + 1) >> 2][(2 * kc + 1) & 3];
                float x2 = ic[2][(2 * kc + 1) >> 2][(2 * kc + 1) & 3];
                n[0][0] += x0 * wb0; n[0][1] += x0 * wb1;
                n[0][2] += x0 * wb2; n[0][3] += x0 * wb3;
                n[1][0] += x1 * wb0; n[1][1] += x1 * wb1;
                n[1][2] += x1 * wb2; n[1][3] += x1 * wb3;
                n[2][0] += x2 * wb0; n[2][1] += x2 * wb1;
                n[2][2] += x2 * wb2; n[2][3] += x2 * wb3;
            }
        }
        #pragma unroll
        for (int ls = 0; ls < 3; ++ls)
            #pragma unroll
            for (int q = 0; q < 4; ++q) ic[ls][q] = n[ls][q];

        // src = mean(ui); usum bit-identical in all 4 lanes
        float cnt = (float)(it + 1);
        f32x4 src[4];
        #pragma unroll
        for (int q = 0; q < 4; ++q) src[q] = usum[q] / cnt;

        // local scores + first-max argmax (global s index), guarded (r11)
        float best = -__builtin_inff();
        int gidx = sbase;
        #pragma unroll
        for (int ls = 0; ls < 3; ++ls) {
            if (ls < 2 || has3) {
                float sc = 0.0f;
                #pragma unroll
                for (int q = 0; q < 4; ++q)
                    #pragma unroll
                    for (int c = 0; c < 4; ++c)
                        sc += ic[ls][q][c] * src[q][c];
                if (sc > best) { best = sc; gidx = sbase + ls; }
            }
        }

        // lexicographic (score, -idx) over the 4-lane group == first-max
        #pragma unroll
        for (int off = 1; off <= 2; off <<= 1) {
            float osc = __shfl_xor(best, off);
            int oidx = __shfl_xor(gidx, off);
            if (osc > best || (osc == best && oidx < gidx)) { best = osc; gidx = oidx; }
        }

        // item_vec broadcast: owner selects, others 0, xor-sum (x+0+0+0 exact)
        f32x4 iv[4];
        #pragma unroll
        for (int q = 0; q < 4; ++q) iv[q] = f32x4{0.f, 0.f, 0.f, 0.f};
        #pragma unroll
        for (int ls = 0; ls < 3; ++ls) {
            if (ls < 2 || has3) {
                bool take = ((sbase + ls) == gidx);
                #pragma unroll
                for (int q = 0; q < 4; ++q)
                    iv[q] = take ? ic[ls][q] : iv[q];
            }
        }
        #pragma unroll
        for (int off = 1; off <= 2; off <<= 1)
            #pragma unroll
            for (int q = 0; q < 4; ++q)
                #pragma unroll
                for (int c = 0; c < 4; ++c)
                    iv[q][c] += __shfl_xor(iv[q][c], off);

        #pragma unroll
        for (int q = 0; q < 4; ++q) {
            usum[q] += iv[q];
            if (quarter == 0) s_out[r * RQ + (it + 1) * 4 + q] = iv[q];
        }
    }

    // ---- Coalesced output: 64 rows x 24 quads = contiguous 24 KB per block.
    __syncthreads();
    f32x4* out4 = (f32x4*)out;
    const size_t obase = (size_t)blockIdx.x * RPB * OUTQ;
    #pragma unroll
    for (int k = 0; k < (RPB * OUTQ) / NT; ++k) {   // 6 iterations
        int j = t + k * NT;
        int row = j / OUTQ;
        int q = j - row * OUTQ;
        out4[obase + j] = s_out[row * RQ + q];
    }
}

extern "C" void kernel_launch(void* const* d_in, const int* in_sizes, int n_in,
                              void* d_out, int out_size, void* d_ws, size_t ws_size,
                              hipStream_t stream) {
    const float* user_intent = (const float*)d_in[0];
    const float* item_corpus = (const float*)d_in[1];
    const float* W_proj      = (const float*)d_in[2];
    const float* b_proj      = (const float*)d_in[3];
    const float* W_k         = (const float*)d_in[4];
    const float* b_k         = (const float*)d_in[5];
    float* out = (float*)d_out;

    const int bs = 65536;
    hipLaunchKernelGGL(attn_greedy_kernel,
                       dim3(bs / RPB), dim3(NT), 0, stream,
                       user_intent, item_corpus, W_proj, b_proj, W_k, b_k, out);
}